// Round 5
// baseline (408.864 us; speedup 1.0000x reference)
//
#include <hip/hip_runtime.h>

typedef __attribute__((ext_vector_type(8))) short short8;
typedef __attribute__((ext_vector_type(4))) short bf16x4;
typedef __attribute__((ext_vector_type(4))) float f32x4;

#define DEV __device__ __forceinline__

DEV unsigned short f2bf(float f) {
    unsigned int u = __builtin_bit_cast(unsigned int, f);
    u += 0x7fffu + ((u >> 16) & 1u);
    return (unsigned short)(u >> 16);
}

#define GLOAD16(gp, lp)                                                        \
    __builtin_amdgcn_global_load_lds(                                          \
        (const __attribute__((address_space(1))) void*)(gp),                   \
        (__attribute__((address_space(3))) void*)(lp), 16, 0, 0)

// ------------------------------------------------------------- ln_bf16 ----
__global__ __launch_bounds__(256) void ln_bf16(
    const float* __restrict__ hidden, const float* __restrict__ inputs,
    const float* __restrict__ ln1w, const float* __restrict__ ln1b,
    const float* __restrict__ ln2w, const float* __restrict__ ln2b,
    unsigned short* __restrict__ LNh, unsigned short* __restrict__ LNx)
{
    int row = blockIdx.x * 4 + (threadIdx.x >> 6);
    int lane = threadIdx.x & 63;
    const float *src, *wp, *bp; unsigned short* dst;
    if (row < 4096) { src = hidden + (size_t)row * 1024; wp = ln1w; bp = ln1b; dst = LNh + (size_t)row * 1024; }
    else { int r = row - 4096; src = inputs + (size_t)r * 1024; wp = ln2w; bp = ln2b; dst = LNx + (size_t)r * 1024; }

    f32x4 v[4];
    float s = 0.f, ss = 0.f;
#pragma unroll
    for (int i = 0; i < 4; ++i) {
        v[i] = *reinterpret_cast<const f32x4*>(src + i * 256 + lane * 4);
#pragma unroll
        for (int j = 0; j < 4; ++j) { s += v[i][j]; ss += v[i][j] * v[i][j]; }
    }
#pragma unroll
    for (int off = 32; off >= 1; off >>= 1) { s += __shfl_xor(s, off); ss += __shfl_xor(ss, off); }
    float mu = s * (1.f / 1024.f);
    float var = fmaxf(ss * (1.f / 1024.f) - mu * mu, 0.f);
    float rs = rsqrtf(var + 1e-5f);
#pragma unroll
    for (int i = 0; i < 4; ++i) {
        f32x4 wv = *reinterpret_cast<const f32x4*>(wp + i * 256 + lane * 4);
        f32x4 bv = *reinterpret_cast<const f32x4*>(bp + i * 256 + lane * 4);
        bf16x4 o;
#pragma unroll
        for (int j = 0; j < 4; ++j) o[j] = (short)f2bf((v[i][j] - mu) * rs * wv[j] + bv[j]);
        *reinterpret_cast<bf16x4*>(dst + i * 256 + lane * 4) = o;
    }
}

// ------------------------------------------------------------- convert ----
__global__ __launch_bounds__(256) void convert_w(
    const float* __restrict__ Wq, const float* __restrict__ Wk, const float* __restrict__ Wv,
    unsigned short* __restrict__ oq, unsigned short* __restrict__ ok_, unsigned short* __restrict__ ov)
{
    unsigned tid = blockIdx.x * 256 + threadIdx.x;
    int arr = tid >> 17;
    size_t off = (size_t)(tid & 131071u) * 8;
    const float* s = (arr == 0) ? Wq : (arr == 1) ? Wk : Wv;
    unsigned short* d = (arr == 0) ? oq : (arr == 1) ? ok_ : ov;
    f32x4 a = *reinterpret_cast<const f32x4*>(s + off);
    f32x4 b = *reinterpret_cast<const f32x4*>(s + off + 4);
    short8 r;
#pragma unroll
    for (int j = 0; j < 4; ++j) { r[j] = (short)f2bf(a[j]); r[j + 4] = (short)f2bf(b[j]); }
    *reinterpret_cast<short8*>(d + off) = r;
}

// ------------------------------------------------- gemm256 (8-phase) ----
// C[m,n] = sum_k A[m,k]*W[n,k] + bias; BM=BN=256, BK=64, 8 waves (2Mx4N).
// LDS: A/B double-slot (2 K-tiles, 128 KiB). Per phase: stage 1 half-tile
// (2 x global_load_lds, pre-swizzled src) + 8 x ds_read_b128 (swizzled) +
// 16 MFMA in setprio(1). One raw s_barrier per phase; vmcnt(0) only at the
// two slot boundaries (phases 0,4). Stage-after-consume => race-free:
//   phases 0-3: compute slot0 (K-tile 2u),  stage slot1 <- K-tile 2u+1
//   phases 4-7: compute slot1 (K-tile 2u+1),stage slot0 <- K-tile 2u+2
// nt >= tsplit: output written transposed per head into Vt[b][h][d][kv].
__global__ __launch_bounds__(512, 2) void gemm256(
    const unsigned short* __restrict__ A, const unsigned short* __restrict__ W,
    const float* __restrict__ b0, const float* __restrict__ b1,
    unsigned short* __restrict__ Cn, unsigned short* __restrict__ Vt,
    int mtiles, int tsplit)
{
    __shared__ __align__(16) char smemc[131072];   // A: [2][256][64]b16 @0, B: @65536

    int t = threadIdx.x, lane = t & 63, w = t >> 6, g = lane >> 4, lr = lane & 15;
    int wr = w >> 2, wcn = w & 3;
    int R0 = wr * 128, C0 = wcn * 64;

    int nwg = gridDim.x;
    int id = blockIdx.x;
    int swz = (id & 7) * (nwg >> 3) + (id >> 3);
    int mt = swz % mtiles, nt = swz / mtiles;
    int m0 = mt * 256, n0 = nt * 256;

    const unsigned short* Ap = A + (size_t)m0 * 1024;
    const unsigned short* Wp = W + (size_t)n0 * 1024;

    f32x4 acc[8][4];
#pragma unroll
    for (int i = 0; i < 8; ++i)
#pragma unroll
        for (int j = 0; j < 4; ++j) acc[i][j] = (f32x4)0.f;

    // stage one half-tile: sel 0=A-h0, 1=A-h1, 2=B-h0, 3=B-h1
    auto STAGE = [&](int slot, int kt, int sel) {
        const unsigned short* P = (sel < 2) ? Ap : Wp;
        char* ldsb = smemc + ((sel < 2) ? 0 : 65536) + slot * 32768;
        int h = sel & 1;
#pragma unroll
        for (int i = 0; i < 2; ++i) {
            int rtb = h * 128 + i * 64 + w * 8;
            int rt = rtb + (lane >> 3);
            int sc = ((lane & 7) * 16) ^ ((rt & 7) << 4);
            const char* gp = (const char*)(P + (size_t)rt * 1024 + kt * 64) + sc;
            GLOAD16(gp, ldsb + rtb * 128);
        }
    };

    // prologue: K-tile 0 into slot 0
    STAGE(0, 0, 0); STAGE(0, 0, 1); STAGE(0, 0, 2); STAGE(0, 0, 3);

    for (int u = 0; u < 8; ++u) {
#pragma unroll
        for (int p = 0; p < 8; ++p) {
            if (p == 0 || p == 4) asm volatile("s_waitcnt vmcnt(0)" ::: "memory");
            asm volatile("s_barrier" ::: "memory");
            if (p < 4)       STAGE(1, 2 * u + 1, p);
            else if (u < 7)  STAGE(0, 2 * u + 2, p - 4);

            const int cs = p >> 2, mq = p & 1, ks = (p >> 1) & 1;
            const char* Ab = smemc + cs * 32768;
            const char* Bb = smemc + 65536 + cs * 32768;
            int cb0 = ks * 64 + g * 16;
            short8 af[4], bfv[4];
#pragma unroll
            for (int a = 0; a < 4; ++a) {
                int r = R0 + (mq * 4 + a) * 16 + lr;
                af[a] = *reinterpret_cast<const short8*>(Ab + r * 128 + (cb0 ^ ((r & 7) << 4)));
            }
#pragma unroll
            for (int ni = 0; ni < 4; ++ni) {
                int r = C0 + ni * 16 + lr;
                bfv[ni] = *reinterpret_cast<const short8*>(Bb + r * 128 + (cb0 ^ ((r & 7) << 4)));
            }
            __builtin_amdgcn_s_setprio(1);
#pragma unroll
            for (int a = 0; a < 4; ++a)
#pragma unroll
                for (int ni = 0; ni < 4; ++ni)
                    acc[mq * 4 + a][ni] =
                        __builtin_amdgcn_mfma_f32_16x16x32_bf16(af[a], bfv[ni], acc[mq * 4 + a][ni], 0, 0, 0);
            __builtin_amdgcn_s_setprio(0);
        }
    }
    __syncthreads();

    unsigned short* CtS = (unsigned short*)smemc;   // [128][272]
    if (nt < tsplit) {
        // normal epilogue, two 128-row chunks
#pragma unroll
        for (int mh = 0; mh < 2; ++mh) {
            if (mh) __syncthreads();
            if (wr == mh) {
#pragma unroll
                for (int ni = 0; ni < 4; ++ni) {
                    int c = C0 + ni * 16 + lr;
                    float bvv = b0[n0 + c];
#pragma unroll
                    for (int mi = 0; mi < 8; ++mi)
#pragma unroll
                        for (int j = 0; j < 4; ++j)
                            CtS[(mi * 16 + g * 4 + j) * 272 + c] = f2bf(acc[mi][ni][j] + bvv);
                }
            }
            __syncthreads();
#pragma unroll
            for (int it = 0; it < 8; ++it) {
                int u2 = it * 512 + t;
                int row = u2 >> 5, c16 = u2 & 31;
                *reinterpret_cast<short8*>(Cn + (size_t)(m0 + mh * 128 + row) * 1024 + n0 + c16 * 8) =
                    *reinterpret_cast<const short8*>(&CtS[row * 272 + c16 * 8]);
            }
        }
    } else {
        // transposed epilogue: two head-chunks of 128 d-rows x 256 kv
        int hbase = (nt - tsplit) * 2;
        int b = m0 >> 12, kv0 = m0 & 4095;
#pragma unroll
        for (int ch = 0; ch < 2; ++ch) {
            if (ch) __syncthreads();
            if ((wcn >> 1) == ch) {
#pragma unroll
                for (int ni = 0; ni < 4; ++ni) {
                    int rowc = (wcn & 1) * 64 + ni * 16 + lr;        // d within chunk
                    float bvv = b1[n0 - 1024 + ch * 128 + rowc];
#pragma unroll
                    for (int mi = 0; mi < 8; ++mi)
#pragma unroll
                        for (int j = 0; j < 4; ++j)
                            CtS[rowc * 272 + wr * 128 + mi * 16 + g * 4 + j] = f2bf(acc[mi][ni][j] + bvv);
                }
            }
            __syncthreads();
            unsigned short* dst = Vt + ((size_t)(b * 8 + hbase + ch) * 128) * 4096 + kv0;
#pragma unroll
            for (int it = 0; it < 8; ++it) {
                int u2 = it * 512 + t;
                int row = u2 >> 5, c16 = u2 & 31;
                *reinterpret_cast<short8*>(dst + (size_t)row * 4096 + c16 * 8) =
                    *reinterpret_cast<const short8*>(&CtS[row * 272 + c16 * 8]);
            }
        }
    }
}

// ----------------------------------------------------------- attention ----
// 8 waves x 16 q-rows (128-q tile), KVBLK=64, double-buffered gload_lds K/Vt,
// one barrier per chunk. V comes pre-transposed from the GEMM (VtG[b][h][d][kv]).
__global__ __launch_bounds__(512, 1) void attn_kernel(
    const unsigned short* __restrict__ Qm, const unsigned short* __restrict__ Km,
    const unsigned short* __restrict__ VtG, const float* __restrict__ hidden,
    float* __restrict__ out)
{
    __shared__ __align__(16) unsigned short Kl[2][64 * 128];
    __shared__ __align__(16) unsigned short Vt[2][128 * 64];
    __shared__ __align__(16) unsigned short Pl[128 * 64];

    int t = threadIdx.x, lane = t & 63, w = t >> 6, g = lane >> 4, lr = lane & 15;
    int swz = (blockIdx.x & 7) * 32 + (blockIdx.x >> 3);
    int qt = swz & 3, h = (swz >> 2) & 7, b = swz >> 5;

    short8 qf[4];
#pragma unroll
    for (int kk = 0; kk < 4; ++kk)
        qf[kk] = *reinterpret_cast<const short8*>(
            Qm + (size_t)(b * 512 + qt * 128 + w * 16 + lr) * 1024 + h * 128 + kk * 32 + g * 8);

    float m_r[4], l_r[4];
    f32x4 oacc[8];
#pragma unroll
    for (int j = 0; j < 4; ++j) { m_r[j] = -__builtin_inff(); l_r[j] = 0.f; }
#pragma unroll
    for (int nf = 0; nf < 8; ++nf) oacc[nf] = (f32x4)0.f;

    const float SCALE = 0.08838834764831845f;
    const float LOG2E = 1.4426950408889634f;
    const float K1 = SCALE * LOG2E;

    size_t kbase = (size_t)b * 4096 * 1024 + h * 128;
    size_t vbase = ((size_t)(b * 8 + h)) * 128 * 4096;

    auto STAGE = [&](int buf, int c) {
        int kv0 = c * 64;
#pragma unroll
        for (int i = 0; i < 2; ++i) {
            int row = w * 8 + i * 4 + (lane >> 4);
            int cb = ((lane & 15) * 16) ^ ((row & 7) << 4);
            const char* gp = (const char*)(Km + kbase + (size_t)(kv0 + row) * 1024) + cb;
            GLOAD16(gp, &Kl[buf][(w * 8 + i * 4) * 128]);
        }
#pragma unroll
        for (int i = 0; i < 2; ++i) {
            int d = w * 16 + i * 8 + (lane >> 3);
            int cb = ((lane & 7) * 16) ^ ((d & 7) << 4);
            const char* gp = (const char*)(VtG + vbase + (size_t)d * 4096 + kv0) + cb;
            GLOAD16(gp, &Vt[buf][(w * 16 + i * 8) * 64]);
        }
    };

    STAGE(0, 0);
    for (int c = 0; c < 64; ++c) {
        int cur = c & 1;
        __syncthreads();
        if (c < 63) STAGE(cur ^ 1, c + 1);

        f32x4 sacc[4];
#pragma unroll
        for (int nf = 0; nf < 4; ++nf) sacc[nf] = (f32x4)0.f;
#pragma unroll
        for (int kk = 0; kk < 4; ++kk) {
            int cb0 = kk * 64 + g * 16;
            short8 bfr[4];
#pragma unroll
            for (int nf = 0; nf < 4; ++nf) {
                int row = nf * 16 + lr;
                bfr[nf] = *reinterpret_cast<const short8*>(
                    (const char*)&Kl[cur][0] + row * 256 + (cb0 ^ ((row & 7) << 4)));
            }
#pragma unroll
            for (int nf = 0; nf < 4; ++nf)
                sacc[nf] = __builtin_amdgcn_mfma_f32_16x16x32_bf16(qf[kk], bfr[nf], sacc[nf], 0, 0, 0);
        }

#pragma unroll
        for (int j = 0; j < 4; ++j) {
            float rowmax = fmaxf(fmaxf(sacc[0][j], sacc[1][j]), fmaxf(sacc[2][j], sacc[3][j]));
            rowmax *= SCALE;
#pragma unroll
            for (int off = 1; off < 16; off <<= 1)
                rowmax = fmaxf(rowmax, __shfl_xor(rowmax, off));
            float mold = m_r[j];
            float mnew = fmaxf(mold, rowmax);
            float corr = exp2f((mold - mnew) * LOG2E);
            float mn2 = mnew * LOG2E;
            float rsum = 0.f;
            int prow = w * 16 + g * 4 + j;
            int rswz = (prow & 7) << 4;
#pragma unroll
            for (int nf = 0; nf < 4; ++nf) {
                float p = exp2f(sacc[nf][j] * K1 - mn2);
                rsum += p;
                *reinterpret_cast<unsigned short*>(
                    (char*)Pl + prow * 128 + ((nf * 32 + lr * 2) ^ rswz)) = f2bf(p);
            }
#pragma unroll
            for (int off = 1; off < 16; off <<= 1)
                rsum += __shfl_xor(rsum, off);
            l_r[j] = l_r[j] * corr + rsum;
            m_r[j] = mnew;
#pragma unroll
            for (int nf = 0; nf < 8; ++nf) oacc[nf][j] *= corr;
        }
        asm volatile("s_waitcnt lgkmcnt(0)" ::: "memory");

#pragma unroll
        for (int kp = 0; kp < 2; ++kp) {
            int cb0 = kp * 64 + g * 16;
            int prow = w * 16 + lr;
            short8 pa = *reinterpret_cast<const short8*>(
                (const char*)Pl + prow * 128 + (cb0 ^ ((prow & 7) << 4)));
#pragma unroll
            for (int nf = 0; nf < 8; ++nf) {
                int d = nf * 16 + lr;
                short8 vb = *reinterpret_cast<const short8*>(
                    (const char*)&Vt[cur][0] + d * 128 + (cb0 ^ ((d & 7) << 4)));
                oacc[nf] = __builtin_amdgcn_mfma_f32_16x16x32_bf16(pa, vb, oacc[nf], 0, 0, 0);
            }
        }
    }

#pragma unroll
    for (int j = 0; j < 4; ++j) {
        float inv = 1.f / l_r[j];
        int q = qt * 128 + w * 16 + g * 4 + j;
        size_t base = (size_t)(b * 512 + q) * 1024 + h * 128;
#pragma unroll
        for (int nf = 0; nf < 8; ++nf) {
            int d = nf * 16 + lr;
            out[base + d] = hidden[base + d] + oacc[nf][j] * inv;
        }
    }
}

// ---------------------------------------------------------------- host ----
extern "C" void kernel_launch(void* const* d_in, const int* in_sizes, int n_in,
                              void* d_out, int out_size, void* d_ws, size_t ws_size,
                              hipStream_t stream) {
    const float* hidden = (const float*)d_in[0];
    const float* inputs = (const float*)d_in[1];
    const float* ln1w   = (const float*)d_in[2];
    const float* ln1b   = (const float*)d_in[3];
    const float* ln2w   = (const float*)d_in[4];
    const float* ln2b   = (const float*)d_in[5];
    const float* Wq     = (const float*)d_in[6];
    const float* bq     = (const float*)d_in[7];
    const float* Wk     = (const float*)d_in[8];
    const float* bk     = (const float*)d_in[9];
    const float* Wv     = (const float*)d_in[10];
    const float* bv     = (const float*)d_in[11];
    float* out = (float*)d_out;
    char* ws = (char*)d_ws;

    unsigned short* LNh = (unsigned short*)ws;        // 4096x1024 bf16
    unsigned short* LNx = LNh + 4194304;              // 32768x1024
    unsigned short* WqB = LNx + 33554432;             // Wq, then Wk|Wv contiguous
    unsigned short* WkB = WqB + 1048576;
    unsigned short* WvB = WkB + 1048576;
    unsigned short* Qm  = WvB + 1048576;              // 4096x1024
    unsigned short* Km  = Qm + 4194304;               // 32768x1024
    unsigned short* VtG = Km + 33554432;              // [b][h][128 d][4096 kv]

    ln_bf16<<<dim3(9216), dim3(256), 0, stream>>>(hidden, inputs, ln1w, ln1b, ln2w, ln2b, LNh, LNx);
    convert_w<<<dim3(1536), dim3(256), 0, stream>>>(Wq, Wk, Wv, WqB, WkB, WvB);
    // Q: M=4096 (16 mtiles), N=1024 (4 ntiles), never transposed
    gemm256<<<dim3(64), dim3(512), 0, stream>>>(LNh, WqB, bq, bq, Qm, Qm, 16, 4);
    // K|V: M=32768 (128 mtiles), N=2048 (8 ntiles); nt>=4 -> V transposed
    gemm256<<<dim3(1024), dim3(512), 0, stream>>>(LNx, WkB, bk, bv, Km, VtG, 128, 4);
    attn_kernel<<<dim3(256), dim3(512), 0, stream>>>(Qm, Km, VtG, hidden, out);
}

// Round 6
// 336.603 us; speedup vs baseline: 1.2147x; 1.2147x over previous
//
#include <hip/hip_runtime.h>

typedef __attribute__((ext_vector_type(8))) short short8;
typedef __attribute__((ext_vector_type(4))) short bf16x4;
typedef __attribute__((ext_vector_type(4))) float f32x4;

#define DEV __device__ __forceinline__

DEV unsigned short f2bf(float f) {
    unsigned int u = __builtin_bit_cast(unsigned int, f);
    u += 0x7fffu + ((u >> 16) & 1u);
    return (unsigned short)(u >> 16);
}

#define GLOAD16(gp, lp)                                                        \
    __builtin_amdgcn_global_load_lds(                                          \
        (const __attribute__((address_space(1))) void*)(gp),                   \
        (__attribute__((address_space(3))) void*)(lp), 16, 0, 0)

// ------------------------------------------------------------- ln_bf16 ----
__global__ __launch_bounds__(256) void ln_bf16(
    const float* __restrict__ hidden, const float* __restrict__ inputs,
    const float* __restrict__ ln1w, const float* __restrict__ ln1b,
    const float* __restrict__ ln2w, const float* __restrict__ ln2b,
    unsigned short* __restrict__ LNh, unsigned short* __restrict__ LNx)
{
    int row = blockIdx.x * 4 + (threadIdx.x >> 6);
    int lane = threadIdx.x & 63;
    const float *src, *wp, *bp; unsigned short* dst;
    if (row < 4096) { src = hidden + (size_t)row * 1024; wp = ln1w; bp = ln1b; dst = LNh + (size_t)row * 1024; }
    else { int r = row - 4096; src = inputs + (size_t)r * 1024; wp = ln2w; bp = ln2b; dst = LNx + (size_t)r * 1024; }

    f32x4 v[4];
    float s = 0.f, ss = 0.f;
#pragma unroll
    for (int i = 0; i < 4; ++i) {
        v[i] = *reinterpret_cast<const f32x4*>(src + i * 256 + lane * 4);
#pragma unroll
        for (int j = 0; j < 4; ++j) { s += v[i][j]; ss += v[i][j] * v[i][j]; }
    }
#pragma unroll
    for (int off = 32; off >= 1; off >>= 1) { s += __shfl_xor(s, off); ss += __shfl_xor(ss, off); }
    float mu = s * (1.f / 1024.f);
    float var = fmaxf(ss * (1.f / 1024.f) - mu * mu, 0.f);
    float rs = rsqrtf(var + 1e-5f);
#pragma unroll
    for (int i = 0; i < 4; ++i) {
        f32x4 wv = *reinterpret_cast<const f32x4*>(wp + i * 256 + lane * 4);
        f32x4 bv = *reinterpret_cast<const f32x4*>(bp + i * 256 + lane * 4);
        bf16x4 o;
#pragma unroll
        for (int j = 0; j < 4; ++j) o[j] = (short)f2bf((v[i][j] - mu) * rs * wv[j] + bv[j]);
        *reinterpret_cast<bf16x4*>(dst + i * 256 + lane * 4) = o;
    }
}

// ------------------------------------------------------------- convert ----
__global__ __launch_bounds__(256) void convert_w(
    const float* __restrict__ Wq, const float* __restrict__ Wk, const float* __restrict__ Wv,
    unsigned short* __restrict__ oq, unsigned short* __restrict__ ok_, unsigned short* __restrict__ ov)
{
    unsigned tid = blockIdx.x * 256 + threadIdx.x;
    int arr = tid >> 17;
    size_t off = (size_t)(tid & 131071u) * 8;
    const float* s = (arr == 0) ? Wq : (arr == 1) ? Wk : Wv;
    unsigned short* d = (arr == 0) ? oq : (arr == 1) ? ok_ : ov;
    f32x4 a = *reinterpret_cast<const f32x4*>(s + off);
    f32x4 b = *reinterpret_cast<const f32x4*>(s + off + 4);
    short8 r;
#pragma unroll
    for (int j = 0; j < 4; ++j) { r[j] = (short)f2bf(a[j]); r[j + 4] = (short)f2bf(b[j]); }
    *reinterpret_cast<short8*>(d + off) = r;
}

// --------------------------------------------- gemm_bt (Q projection) ----
// 128x128 tile, BK=64, m97 structure. C[m,n] = sum_k A[m,k]*W[n,k] + bias.
__global__ __launch_bounds__(256) void gemm_bt(
    const unsigned short* __restrict__ A,
    const unsigned short* __restrict__ W, const float* __restrict__ bias,
    unsigned short* __restrict__ C)
{
    __shared__ __align__(16) unsigned short smem[16384];
    unsigned short* As = smem;
    unsigned short* Bs = smem + 8192;

    int t = threadIdx.x, lane = t & 63, w = t >> 6;
    int wr = w >> 1, wc = w & 1, g = lane >> 4, lr = lane & 15;
    int m0 = blockIdx.x * 128;
    int n0 = blockIdx.y * 128;

    f32x4 acc[4][4];
#pragma unroll
    for (int i = 0; i < 4; ++i)
#pragma unroll
        for (int j = 0; j < 4; ++j) acc[i][j] = (f32x4)0.f;

    int srow = lane >> 3;
    int scb  = (lane & 7) * 16;

    for (int kb = 0; kb < 1024; kb += 64) {
#pragma unroll
        for (int i = 0; i < 4; ++i) {
            int row = i * 32 + w * 8 + srow;
            int cb = scb ^ ((row & 7) << 4);
            const char* ga = (const char*)(A + (size_t)(m0 + row) * 1024 + kb) + cb;
            GLOAD16(ga, &As[(size_t)(i * 32 + w * 8) * 64]);
            const char* gb = (const char*)(W + (size_t)(n0 + row) * 1024 + kb) + cb;
            GLOAD16(gb, &Bs[(size_t)(i * 32 + w * 8) * 64]);
        }
        __syncthreads();
#pragma unroll
        for (int kk = 0; kk < 2; ++kk) {
            int cb0 = kk * 64 + g * 16;
            short8 af[4], bf[4];
#pragma unroll
            for (int mi = 0; mi < 4; ++mi) {
                int row = wr * 64 + mi * 16 + lr;
                af[mi] = *reinterpret_cast<const short8*>(
                    (const char*)As + row * 128 + (cb0 ^ ((row & 7) << 4)));
            }
#pragma unroll
            for (int ni = 0; ni < 4; ++ni) {
                int row = wc * 64 + ni * 16 + lr;
                bf[ni] = *reinterpret_cast<const short8*>(
                    (const char*)Bs + row * 128 + (cb0 ^ ((row & 7) << 4)));
            }
#pragma unroll
            for (int mi = 0; mi < 4; ++mi)
#pragma unroll
                for (int ni = 0; ni < 4; ++ni)
                    acc[mi][ni] = __builtin_amdgcn_mfma_f32_16x16x32_bf16(af[mi], bf[ni], acc[mi][ni], 0, 0, 0);
        }
        __syncthreads();
    }

    unsigned short* Ct = smem;
#pragma unroll
    for (int ni = 0; ni < 4; ++ni) {
        int coll = wc * 64 + ni * 16 + lr;
        float bv = bias[n0 + coll];
#pragma unroll
        for (int mi = 0; mi < 4; ++mi)
#pragma unroll
            for (int j = 0; j < 4; ++j) {
                int rowl = wr * 64 + mi * 16 + g * 4 + j;
                Ct[rowl * 128 + coll] = f2bf(acc[mi][ni][j] + bv);
            }
    }
    __syncthreads();
#pragma unroll
    for (int i = 0; i < 8; ++i) {
        int idx = i * 2048 + t * 8;
        int row = idx >> 7, col = idx & 127;
        *reinterpret_cast<short8*>(C + (size_t)(m0 + row) * 1024 + n0 + col) =
            *reinterpret_cast<const short8*>(&Ct[idx]);
    }
}

// ------------------------------------------------- gemm256 (8-phase) ----
// unchanged from round 5 (verified): K|V projections; V written transposed.
__global__ __launch_bounds__(512, 2) void gemm256(
    const unsigned short* __restrict__ A, const unsigned short* __restrict__ W,
    const float* __restrict__ b0, const float* __restrict__ b1,
    unsigned short* __restrict__ Cn, unsigned short* __restrict__ Vt,
    int mtiles, int tsplit)
{
    __shared__ __align__(16) char smemc[131072];

    int t = threadIdx.x, lane = t & 63, w = t >> 6, g = lane >> 4, lr = lane & 15;
    int wr = w >> 2, wcn = w & 3;
    int R0 = wr * 128, C0 = wcn * 64;

    int nwg = gridDim.x;
    int id = blockIdx.x;
    int swz = (id & 7) * (nwg >> 3) + (id >> 3);
    int mt = swz % mtiles, nt = swz / mtiles;
    int m0 = mt * 256, n0 = nt * 256;

    const unsigned short* Ap = A + (size_t)m0 * 1024;
    const unsigned short* Wp = W + (size_t)n0 * 1024;

    f32x4 acc[8][4];
#pragma unroll
    for (int i = 0; i < 8; ++i)
#pragma unroll
        for (int j = 0; j < 4; ++j) acc[i][j] = (f32x4)0.f;

    auto STAGE = [&](int slot, int kt, int sel) {
        const unsigned short* P = (sel < 2) ? Ap : Wp;
        char* ldsb = smemc + ((sel < 2) ? 0 : 65536) + slot * 32768;
        int h = sel & 1;
#pragma unroll
        for (int i = 0; i < 2; ++i) {
            int rtb = h * 128 + i * 64 + w * 8;
            int rt = rtb + (lane >> 3);
            int sc = ((lane & 7) * 16) ^ ((rt & 7) << 4);
            const char* gp = (const char*)(P + (size_t)rt * 1024 + kt * 64) + sc;
            GLOAD16(gp, ldsb + rtb * 128);
        }
    };

    STAGE(0, 0, 0); STAGE(0, 0, 1); STAGE(0, 0, 2); STAGE(0, 0, 3);

    for (int u = 0; u < 8; ++u) {
#pragma unroll
        for (int p = 0; p < 8; ++p) {
            if (p == 0 || p == 4) asm volatile("s_waitcnt vmcnt(0)" ::: "memory");
            asm volatile("s_barrier" ::: "memory");
            if (p < 4)       STAGE(1, 2 * u + 1, p);
            else if (u < 7)  STAGE(0, 2 * u + 2, p - 4);

            const int cs = p >> 2, mq = p & 1, ks = (p >> 1) & 1;
            const char* Ab = smemc + cs * 32768;
            const char* Bb = smemc + 65536 + cs * 32768;
            int cb0 = ks * 64 + g * 16;
            short8 af[4], bfv[4];
#pragma unroll
            for (int a = 0; a < 4; ++a) {
                int r = R0 + (mq * 4 + a) * 16 + lr;
                af[a] = *reinterpret_cast<const short8*>(Ab + r * 128 + (cb0 ^ ((r & 7) << 4)));
            }
#pragma unroll
            for (int ni = 0; ni < 4; ++ni) {
                int r = C0 + ni * 16 + lr;
                bfv[ni] = *reinterpret_cast<const short8*>(Bb + r * 128 + (cb0 ^ ((r & 7) << 4)));
            }
            __builtin_amdgcn_s_setprio(1);
#pragma unroll
            for (int a = 0; a < 4; ++a)
#pragma unroll
                for (int ni = 0; ni < 4; ++ni)
                    acc[mq * 4 + a][ni] =
                        __builtin_amdgcn_mfma_f32_16x16x32_bf16(af[a], bfv[ni], acc[mq * 4 + a][ni], 0, 0, 0);
            __builtin_amdgcn_s_setprio(0);
        }
    }
    __syncthreads();

    unsigned short* CtS = (unsigned short*)smemc;
    if (nt < tsplit) {
#pragma unroll
        for (int mh = 0; mh < 2; ++mh) {
            if (mh) __syncthreads();
            if (wr == mh) {
#pragma unroll
                for (int ni = 0; ni < 4; ++ni) {
                    int c = C0 + ni * 16 + lr;
                    float bvv = b0[n0 + c];
#pragma unroll
                    for (int mi = 0; mi < 8; ++mi)
#pragma unroll
                        for (int j = 0; j < 4; ++j)
                            CtS[(mi * 16 + g * 4 + j) * 272 + c] = f2bf(acc[mi][ni][j] + bvv);
                }
            }
            __syncthreads();
#pragma unroll
            for (int it = 0; it < 8; ++it) {
                int u2 = it * 512 + t;
                int row = u2 >> 5, c16 = u2 & 31;
                *reinterpret_cast<short8*>(Cn + (size_t)(m0 + mh * 128 + row) * 1024 + n0 + c16 * 8) =
                    *reinterpret_cast<const short8*>(&CtS[row * 272 + c16 * 8]);
            }
        }
    } else {
        int hbase = (nt - tsplit) * 2;
        int b = m0 >> 12, kv0 = m0 & 4095;
#pragma unroll
        for (int ch = 0; ch < 2; ++ch) {
            if (ch) __syncthreads();
            if ((wcn >> 1) == ch) {
#pragma unroll
                for (int ni = 0; ni < 4; ++ni) {
                    int rowc = (wcn & 1) * 64 + ni * 16 + lr;
                    float bvv = b1[n0 - 1024 + ch * 128 + rowc];
#pragma unroll
                    for (int mi = 0; mi < 8; ++mi)
#pragma unroll
                        for (int j = 0; j < 4; ++j)
                            CtS[rowc * 272 + wr * 128 + mi * 16 + g * 4 + j] = f2bf(acc[mi][ni][j] + bvv);
                }
            }
            __syncthreads();
            unsigned short* dst = Vt + ((size_t)(b * 8 + hbase + ch) * 128) * 4096 + kv0;
#pragma unroll
            for (int it = 0; it < 8; ++it) {
                int u2 = it * 512 + t;
                int row = u2 >> 5, c16 = u2 & 31;
                *reinterpret_cast<short8*>(dst + (size_t)row * 4096 + c16 * 8) =
                    *reinterpret_cast<const short8*>(&CtS[row * 272 + c16 * 8]);
            }
        }
    }
}

// ----------------------------------------------------------- attention ----
// 4 waves (256 thr), q-tile 64 (16 q/wave), KVBLK=64, grid 512 -> 2 blk/CU.
// Swapped QK^T (S^T = K*Q^T) -> lane-local P rows; defer-max (m2=0, guarded
// rescale); packed b64 P stores; dbuf K/V via global_load_lds; one raw
// s_barrier + full drain per chunk (staging pipelined one chunk ahead).
__global__ __launch_bounds__(256, 2) void attn_kernel(
    const unsigned short* __restrict__ Qm, const unsigned short* __restrict__ Km,
    const unsigned short* __restrict__ VtG, const float* __restrict__ hidden,
    float* __restrict__ out)
{
    __shared__ __align__(16) unsigned short Kl[2][64 * 128];   // 32 KB
    __shared__ __align__(16) unsigned short Vt[2][128 * 64];   // 32 KB
    __shared__ __align__(16) unsigned short Pl[64 * 64];       //  8 KB

    int t = threadIdx.x, lane = t & 63, w = t >> 6, g = lane >> 4, lr = lane & 15;
    int id = blockIdx.x;
    int swz = (id & 7) * 64 + (id >> 3);      // XCD k <- all of batch k
    int qt = swz & 7, h = (swz >> 3) & 7, b = swz >> 6;

    // Q fragment (B-operand): rows q = qt*64 + w*16 + lr
    short8 qf[4];
#pragma unroll
    for (int kk = 0; kk < 4; ++kk)
        qf[kk] = *reinterpret_cast<const short8*>(
            Qm + (size_t)(b * 512 + qt * 64 + w * 16 + lr) * 1024 + h * 128 + kk * 32 + g * 8);
    asm volatile("s_waitcnt vmcnt(0)" ::: "memory");   // Q in regs before staging counts

    float m2 = 0.f;          // running max, log2 units (row q=lr); defer-max
    float l = 0.f;           // per-lane partial denominator
    f32x4 oacc[8];
#pragma unroll
    for (int nf = 0; nf < 8; ++nf) oacc[nf] = (f32x4)0.f;

    const float SCALE = 0.08838834764831845f;   // 1/sqrt(128)
    const float LOG2E = 1.4426950408889634f;
    const float K1 = SCALE * LOG2E;
    const float THR2 = 11.5f;                   // ~8 nats in log2

    size_t kbase = (size_t)b * 4096 * 1024 + h * 128;
    size_t vbase = ((size_t)(b * 8 + h)) * 128 * 4096;

    auto STAGE_K = [&](int buf, int c) {
        int kv0 = c * 64;
#pragma unroll
        for (int i = 0; i < 4; ++i) {
            int rb = w * 16 + i * 4;
            int row = rb + (lane >> 4);
            int cb = ((lane & 15) * 16) ^ ((row & 7) << 4);
            const char* gp = (const char*)(Km + kbase + (size_t)(kv0 + row) * 1024) + cb;
            GLOAD16(gp, &Kl[buf][rb * 128]);
        }
    };
    auto STAGE_V = [&](int buf, int c) {
        int kv0 = c * 64;
#pragma unroll
        for (int i = 0; i < 4; ++i) {
            int db = w * 32 + i * 8;
            int d = db + (lane >> 3);
            int cb = ((lane & 7) * 16) ^ ((d & 7) << 4);
            const char* gp = (const char*)(VtG + vbase + (size_t)d * 4096 + kv0) + cb;
            GLOAD16(gp, &Vt[buf][db * 64]);
        }
    };

    STAGE_K(0, 0); STAGE_V(0, 0);

    for (int c = 0; c < 64; ++c) {
        int cur = c & 1;
        // all of chunk c's staging landed (issued a full chunk ago); all waves'
        // reads of chunk c-1 retired -> cur^1 buffers free after the barrier.
        asm volatile("s_waitcnt vmcnt(0) lgkmcnt(0)" ::: "memory");
        __builtin_amdgcn_sched_barrier(0);
        __builtin_amdgcn_s_barrier();
        if (c < 63) { STAGE_K(cur ^ 1, c + 1); STAGE_V(cur ^ 1, c + 1); }

        // S^T = K * Q^T : sacc[nf][j] = S[q=lr][kv = nf*16 + g*4 + j]
        f32x4 sacc[4];
#pragma unroll
        for (int nf = 0; nf < 4; ++nf) sacc[nf] = (f32x4)0.f;
#pragma unroll
        for (int kk = 0; kk < 4; ++kk) {
            int cb0 = kk * 64 + g * 16;
            short8 kf[4];
#pragma unroll
            for (int nf = 0; nf < 4; ++nf) {
                int row = nf * 16 + lr;
                kf[nf] = *reinterpret_cast<const short8*>(
                    (const char*)&Kl[cur][0] + row * 256 + (cb0 ^ ((row & 7) << 4)));
            }
            __builtin_amdgcn_s_setprio(1);
#pragma unroll
            for (int nf = 0; nf < 4; ++nf)
                sacc[nf] = __builtin_amdgcn_mfma_f32_16x16x32_bf16(kf[nf], qf[kk], sacc[nf], 0, 0, 0);
            __builtin_amdgcn_s_setprio(0);
        }

        // defer-max online softmax (no cross-lane work on the fast path)
        float smax = sacc[0][0];
#pragma unroll
        for (int nf = 0; nf < 4; ++nf)
#pragma unroll
            for (int j = 0; j < 4; ++j) smax = fmaxf(smax, sacc[nf][j]);
        float s2max = smax * K1;
        if (!__all(s2max <= m2 + THR2)) {          // rare rescale path
            float rm = s2max;
            rm = fmaxf(rm, __shfl_xor(rm, 16));
            rm = fmaxf(rm, __shfl_xor(rm, 32));
            float m2n = fmaxf(m2, rm);
            float corr = exp2f(m2 - m2n);
            l *= corr;
            m2 = m2n;
#pragma unroll
            for (int j = 0; j < 4; ++j) {
                float cj = __shfl(corr, g * 4 + j);
#pragma unroll
                for (int nf = 0; nf < 8; ++nf) oacc[nf][j] *= cj;
            }
        }
        int prow = w * 16 + lr;
        int rsw = (lr & 7) << 4;
#pragma unroll
        for (int nf = 0; nf < 4; ++nf) {
            float p0 = exp2f(sacc[nf][0] * K1 - m2);
            float p1 = exp2f(sacc[nf][1] * K1 - m2);
            float p2 = exp2f(sacc[nf][2] * K1 - m2);
            float p3 = exp2f(sacc[nf][3] * K1 - m2);
            l += (p0 + p1) + (p2 + p3);
            bf16x4 pk;
            pk[0] = (short)f2bf(p0); pk[1] = (short)f2bf(p1);
            pk[2] = (short)f2bf(p2); pk[3] = (short)f2bf(p3);
            *reinterpret_cast<bf16x4*>(
                (char*)Pl + prow * 128 + ((nf * 32 + g * 8) ^ rsw)) = pk;
        }
        asm volatile("s_waitcnt lgkmcnt(0)" ::: "memory");   // own P stores done
        __builtin_amdgcn_sched_barrier(0);

        // O += P * V^T : oacc[nf][j] = O[q = g*4+j][d = nf*16+lr]
#pragma unroll
        for (int kp = 0; kp < 2; ++kp) {
            int cb0 = kp * 64 + g * 16;
            short8 pa = *reinterpret_cast<const short8*>(
                (const char*)Pl + prow * 128 + (cb0 ^ rsw));
#pragma unroll
            for (int nf = 0; nf < 8; ++nf) {
                int d = nf * 16 + lr;
                short8 vb = *reinterpret_cast<const short8*>(
                    (const char*)&Vt[cur][0] + d * 128 + (cb0 ^ ((d & 7) << 4)));
                oacc[nf] = __builtin_amdgcn_mfma_f32_16x16x32_bf16(pa, vb, oacc[nf], 0, 0, 0);
            }
        }
    }

    // epilogue: l row-sum (rows are lr-indexed), then out = hidden + O/l
    l += __shfl_xor(l, 16);
    l += __shfl_xor(l, 32);
#pragma unroll
    for (int j = 0; j < 4; ++j) {
        float lj = __shfl(l, g * 4 + j);
        float inv = 1.f / lj;
        int q = qt * 64 + w * 16 + g * 4 + j;
        size_t base = (size_t)(b * 512 + q) * 1024 + h * 128;
#pragma unroll
        for (int nf = 0; nf < 8; ++nf) {
            int d = nf * 16 + lr;
            out[base + d] = hidden[base + d] + oacc[nf][j] * inv;
        }
    }
}

// ---------------------------------------------------------------- host ----
extern "C" void kernel_launch(void* const* d_in, const int* in_sizes, int n_in,
                              void* d_out, int out_size, void* d_ws, size_t ws_size,
                              hipStream_t stream) {
    const float* hidden = (const float*)d_in[0];
    const float* inputs = (const float*)d_in[1];
    const float* ln1w   = (const float*)d_in[2];
    const float* ln1b   = (const float*)d_in[3];
    const float* ln2w   = (const float*)d_in[4];
    const float* ln2b   = (const float*)d_in[5];
    const float* Wq     = (const float*)d_in[6];
    const float* bq     = (const float*)d_in[7];
    const float* Wk     = (const float*)d_in[8];
    const float* bk     = (const float*)d_in[9];
    const float* Wv     = (const float*)d_in[10];
    const float* bv     = (const float*)d_in[11];
    float* out = (float*)d_out;
    char* ws = (char*)d_ws;

    unsigned short* LNh = (unsigned short*)ws;        // 4096x1024 bf16
    unsigned short* LNx = LNh + 4194304;              // 32768x1024
    unsigned short* WqB = LNx + 33554432;             // Wq, then Wk|Wv contiguous
    unsigned short* WkB = WqB + 1048576;
    unsigned short* WvB = WkB + 1048576;
    unsigned short* Qm  = WvB + 1048576;              // 4096x1024
    unsigned short* Km  = Qm + 4194304;               // 32768x1024
    unsigned short* VtG = Km + 33554432;              // [b][h][128 d][4096 kv]

    ln_bf16<<<dim3(9216), dim3(256), 0, stream>>>(hidden, inputs, ln1w, ln1b, ln2w, ln2b, LNh, LNx);
    convert_w<<<dim3(1536), dim3(256), 0, stream>>>(Wq, Wk, Wv, WqB, WkB, WvB);
    // Q: 128^2 tiles, full-chip grid
    gemm_bt<<<dim3(32, 8), dim3(256), 0, stream>>>(LNh, WqB, bq, Qm);
    // K|V: 256^2 8-phase; M=32768 (128 mtiles), N=2048 (8 ntiles); nt>=4 -> V transposed
    gemm256<<<dim3(1024), dim3(512), 0, stream>>>(LNx, WkB, bk, bv, Km, VtG, 128, 4);
    attn_kernel<<<dim3(512), dim3(256), 0, stream>>>(Qm, Km, VtG, hidden, out);
}

// Round 7
// 336.135 us; speedup vs baseline: 1.2164x; 1.0014x over previous
//
#include <hip/hip_runtime.h>

typedef __attribute__((ext_vector_type(8))) short short8;
typedef __attribute__((ext_vector_type(4))) short bf16x4;
typedef __attribute__((ext_vector_type(4))) float f32x4;

#define DEV __device__ __forceinline__

DEV unsigned short f2bf(float f) {
    unsigned int u = __builtin_bit_cast(unsigned int, f);
    u += 0x7fffu + ((u >> 16) & 1u);
    return (unsigned short)(u >> 16);
}

#define GLOAD16(gp, lp)                                                        \
    __builtin_amdgcn_global_load_lds(                                          \
        (const __attribute__((address_space(1))) void*)(gp),                   \
        (__attribute__((address_space(3))) void*)(lp), 16, 0, 0)

// ------------------------------------------------------------- ln_bf16 ----
__global__ __launch_bounds__(256) void ln_bf16(
    const float* __restrict__ hidden, const float* __restrict__ inputs,
    const float* __restrict__ ln1w, const float* __restrict__ ln1b,
    const float* __restrict__ ln2w, const float* __restrict__ ln2b,
    unsigned short* __restrict__ LNh, unsigned short* __restrict__ LNx)
{
    int row = blockIdx.x * 4 + (threadIdx.x >> 6);
    int lane = threadIdx.x & 63;
    const float *src, *wp, *bp; unsigned short* dst;
    if (row < 4096) { src = hidden + (size_t)row * 1024; wp = ln1w; bp = ln1b; dst = LNh + (size_t)row * 1024; }
    else { int r = row - 4096; src = inputs + (size_t)r * 1024; wp = ln2w; bp = ln2b; dst = LNx + (size_t)r * 1024; }

    f32x4 v[4];
    float s = 0.f, ss = 0.f;
#pragma unroll
    for (int i = 0; i < 4; ++i) {
        v[i] = *reinterpret_cast<const f32x4*>(src + i * 256 + lane * 4);
#pragma unroll
        for (int j = 0; j < 4; ++j) { s += v[i][j]; ss += v[i][j] * v[i][j]; }
    }
#pragma unroll
    for (int off = 32; off >= 1; off >>= 1) { s += __shfl_xor(s, off); ss += __shfl_xor(ss, off); }
    float mu = s * (1.f / 1024.f);
    float var = fmaxf(ss * (1.f / 1024.f) - mu * mu, 0.f);
    float rs = rsqrtf(var + 1e-5f);
#pragma unroll
    for (int i = 0; i < 4; ++i) {
        f32x4 wv = *reinterpret_cast<const f32x4*>(wp + i * 256 + lane * 4);
        f32x4 bv = *reinterpret_cast<const f32x4*>(bp + i * 256 + lane * 4);
        bf16x4 o;
#pragma unroll
        for (int j = 0; j < 4; ++j) o[j] = (short)f2bf((v[i][j] - mu) * rs * wv[j] + bv[j]);
        *reinterpret_cast<bf16x4*>(dst + i * 256 + lane * 4) = o;
    }
}

// ------------------------------------------------------------- convert ----
__global__ __launch_bounds__(256) void convert_w(
    const float* __restrict__ Wq, const float* __restrict__ Wk, const float* __restrict__ Wv,
    unsigned short* __restrict__ oq, unsigned short* __restrict__ ok_, unsigned short* __restrict__ ov)
{
    unsigned tid = blockIdx.x * 256 + threadIdx.x;
    int arr = tid >> 17;
    size_t off = (size_t)(tid & 131071u) * 8;
    const float* s = (arr == 0) ? Wq : (arr == 1) ? Wk : Wv;
    unsigned short* d = (arr == 0) ? oq : (arr == 1) ? ok_ : ov;
    f32x4 a = *reinterpret_cast<const f32x4*>(s + off);
    f32x4 b = *reinterpret_cast<const f32x4*>(s + off + 4);
    short8 r;
#pragma unroll
    for (int j = 0; j < 4; ++j) { r[j] = (short)f2bf(a[j]); r[j + 4] = (short)f2bf(b[j]); }
    *reinterpret_cast<short8*>(d + off) = r;
}

// --------------------------------------------- gemm_bt (Q projection) ----
__global__ __launch_bounds__(256) void gemm_bt(
    const unsigned short* __restrict__ A,
    const unsigned short* __restrict__ W, const float* __restrict__ bias,
    unsigned short* __restrict__ C)
{
    __shared__ __align__(16) unsigned short smem[16384];
    unsigned short* As = smem;
    unsigned short* Bs = smem + 8192;

    int t = threadIdx.x, lane = t & 63, w = t >> 6;
    int wr = w >> 1, wc = w & 1, g = lane >> 4, lr = lane & 15;
    int m0 = blockIdx.x * 128;
    int n0 = blockIdx.y * 128;

    f32x4 acc[4][4];
#pragma unroll
    for (int i = 0; i < 4; ++i)
#pragma unroll
        for (int j = 0; j < 4; ++j) acc[i][j] = (f32x4)0.f;

    int srow = lane >> 3;
    int scb  = (lane & 7) * 16;

    for (int kb = 0; kb < 1024; kb += 64) {
#pragma unroll
        for (int i = 0; i < 4; ++i) {
            int row = i * 32 + w * 8 + srow;
            int cb = scb ^ ((row & 7) << 4);
            const char* ga = (const char*)(A + (size_t)(m0 + row) * 1024 + kb) + cb;
            GLOAD16(ga, &As[(size_t)(i * 32 + w * 8) * 64]);
            const char* gb = (const char*)(W + (size_t)(n0 + row) * 1024 + kb) + cb;
            GLOAD16(gb, &Bs[(size_t)(i * 32 + w * 8) * 64]);
        }
        __syncthreads();
#pragma unroll
        for (int kk = 0; kk < 2; ++kk) {
            int cb0 = kk * 64 + g * 16;
            short8 af[4], bf[4];
#pragma unroll
            for (int mi = 0; mi < 4; ++mi) {
                int row = wr * 64 + mi * 16 + lr;
                af[mi] = *reinterpret_cast<const short8*>(
                    (const char*)As + row * 128 + (cb0 ^ ((row & 7) << 4)));
            }
#pragma unroll
            for (int ni = 0; ni < 4; ++ni) {
                int row = wc * 64 + ni * 16 + lr;
                bf[ni] = *reinterpret_cast<const short8*>(
                    (const char*)Bs + row * 128 + (cb0 ^ ((row & 7) << 4)));
            }
#pragma unroll
            for (int mi = 0; mi < 4; ++mi)
#pragma unroll
                for (int ni = 0; ni < 4; ++ni)
                    acc[mi][ni] = __builtin_amdgcn_mfma_f32_16x16x32_bf16(af[mi], bf[ni], acc[mi][ni], 0, 0, 0);
        }
        __syncthreads();
    }

    unsigned short* Ct = smem;
#pragma unroll
    for (int ni = 0; ni < 4; ++ni) {
        int coll = wc * 64 + ni * 16 + lr;
        float bv = bias[n0 + coll];
#pragma unroll
        for (int mi = 0; mi < 4; ++mi)
#pragma unroll
            for (int j = 0; j < 4; ++j) {
                int rowl = wr * 64 + mi * 16 + g * 4 + j;
                Ct[rowl * 128 + coll] = f2bf(acc[mi][ni][j] + bv);
            }
    }
    __syncthreads();
#pragma unroll
    for (int i = 0; i < 8; ++i) {
        int idx = i * 2048 + t * 8;
        int row = idx >> 7, col = idx & 127;
        *reinterpret_cast<short8*>(C + (size_t)(m0 + row) * 1024 + n0 + col) =
            *reinterpret_cast<const short8*>(&Ct[idx]);
    }
}

// ------------------------------------------------- gemm256 (8-phase) ----
// Changes vs round 6:
//  (1) front-loaded staging: all 8 global_load_lds of a slot issued in one
//      burst at p==0 / p==4 -> ~4 phases of flight before the vmcnt(0) drain.
//  (2) L2-locality swizzle: each XCD owns a contiguous mt range, nt fastest
//      -> consecutive blocks on an XCD share the same A panel (L2 hit).
__global__ __launch_bounds__(512, 2) void gemm256(
    const unsigned short* __restrict__ A, const unsigned short* __restrict__ W,
    const float* __restrict__ b0, const float* __restrict__ b1,
    unsigned short* __restrict__ Cn, unsigned short* __restrict__ Vt,
    int mtiles, int tsplit)
{
    __shared__ __align__(16) char smemc[131072];

    int t = threadIdx.x, lane = t & 63, w = t >> 6, g = lane >> 4, lr = lane & 15;
    int wr = w >> 2, wcn = w & 3;
    int R0 = wr * 128, C0 = wcn * 64;

    int id = blockIdx.x;
    int ntc = gridDim.x / mtiles;              // n-tiles (8)
    int xcd = id & 7, ord = id >> 3;           // hw dispatch: id%8 -> XCD
    int mt = xcd * (mtiles >> 3) + ord / ntc;  // contiguous mt chunk per XCD
    int nt = ord % ntc;                        // nt fastest: A-panel L2 reuse
    int m0 = mt * 256, n0 = nt * 256;

    const unsigned short* Ap = A + (size_t)m0 * 1024;
    const unsigned short* Wp = W + (size_t)n0 * 1024;

    f32x4 acc[8][4];
#pragma unroll
    for (int i = 0; i < 8; ++i)
#pragma unroll
        for (int j = 0; j < 4; ++j) acc[i][j] = (f32x4)0.f;

    auto STAGE = [&](int slot, int kt, int sel) {
        const unsigned short* P = (sel < 2) ? Ap : Wp;
        char* ldsb = smemc + ((sel < 2) ? 0 : 65536) + slot * 32768;
        int h = sel & 1;
#pragma unroll
        for (int i = 0; i < 2; ++i) {
            int rtb = h * 128 + i * 64 + w * 8;
            int rt = rtb + (lane >> 3);
            int sc = ((lane & 7) * 16) ^ ((rt & 7) << 4);
            const char* gp = (const char*)(P + (size_t)rt * 1024 + kt * 64) + sc;
            GLOAD16(gp, ldsb + rtb * 128);
        }
    };

    STAGE(0, 0, 0); STAGE(0, 0, 1); STAGE(0, 0, 2); STAGE(0, 0, 3);

    for (int u = 0; u < 8; ++u) {
#pragma unroll
        for (int p = 0; p < 8; ++p) {
            if (p == 0 || p == 4) asm volatile("s_waitcnt vmcnt(0)" ::: "memory");
            asm volatile("s_barrier" ::: "memory");
            if (p == 0) {                       // burst-stage slot1 <- kt 2u+1
                STAGE(1, 2 * u + 1, 0); STAGE(1, 2 * u + 1, 1);
                STAGE(1, 2 * u + 1, 2); STAGE(1, 2 * u + 1, 3);
            } else if (p == 4 && u < 7) {       // burst-stage slot0 <- kt 2u+2
                STAGE(0, 2 * u + 2, 0); STAGE(0, 2 * u + 2, 1);
                STAGE(0, 2 * u + 2, 2); STAGE(0, 2 * u + 2, 3);
            }

            const int cs = p >> 2, mq = p & 1, ks = (p >> 1) & 1;
            const char* Ab = smemc + cs * 32768;
            const char* Bb = smemc + 65536 + cs * 32768;
            int cb0 = ks * 64 + g * 16;
            short8 af[4], bfv[4];
#pragma unroll
            for (int a = 0; a < 4; ++a) {
                int r = R0 + (mq * 4 + a) * 16 + lr;
                af[a] = *reinterpret_cast<const short8*>(Ab + r * 128 + (cb0 ^ ((r & 7) << 4)));
            }
#pragma unroll
            for (int ni = 0; ni < 4; ++ni) {
                int r = C0 + ni * 16 + lr;
                bfv[ni] = *reinterpret_cast<const short8*>(Bb + r * 128 + (cb0 ^ ((r & 7) << 4)));
            }
            __builtin_amdgcn_s_setprio(1);
#pragma unroll
            for (int a = 0; a < 4; ++a)
#pragma unroll
                for (int ni = 0; ni < 4; ++ni)
                    acc[mq * 4 + a][ni] =
                        __builtin_amdgcn_mfma_f32_16x16x32_bf16(af[a], bfv[ni], acc[mq * 4 + a][ni], 0, 0, 0);
            __builtin_amdgcn_s_setprio(0);
        }
    }
    __syncthreads();

    unsigned short* CtS = (unsigned short*)smemc;
    if (nt < tsplit) {
#pragma unroll
        for (int mh = 0; mh < 2; ++mh) {
            if (mh) __syncthreads();
            if (wr == mh) {
#pragma unroll
                for (int ni = 0; ni < 4; ++ni) {
                    int c = C0 + ni * 16 + lr;
                    float bvv = b0[n0 + c];
#pragma unroll
                    for (int mi = 0; mi < 8; ++mi)
#pragma unroll
                        for (int j = 0; j < 4; ++j)
                            CtS[(mi * 16 + g * 4 + j) * 272 + c] = f2bf(acc[mi][ni][j] + bvv);
                }
            }
            __syncthreads();
#pragma unroll
            for (int it = 0; it < 8; ++it) {
                int u2 = it * 512 + t;
                int row = u2 >> 5, c16 = u2 & 31;
                *reinterpret_cast<short8*>(Cn + (size_t)(m0 + mh * 128 + row) * 1024 + n0 + c16 * 8) =
                    *reinterpret_cast<const short8*>(&CtS[row * 272 + c16 * 8]);
            }
        }
    } else {
        int hbase = (nt - tsplit) * 2;
        int b = m0 >> 12, kv0 = m0 & 4095;
#pragma unroll
        for (int ch = 0; ch < 2; ++ch) {
            if (ch) __syncthreads();
            if ((wcn >> 1) == ch) {
#pragma unroll
                for (int ni = 0; ni < 4; ++ni) {
                    int rowc = (wcn & 1) * 64 + ni * 16 + lr;
                    float bvv = b1[n0 - 1024 + ch * 128 + rowc];
#pragma unroll
                    for (int mi = 0; mi < 8; ++mi)
#pragma unroll
                        for (int j = 0; j < 4; ++j)
                            CtS[rowc * 272 + wr * 128 + mi * 16 + g * 4 + j] = f2bf(acc[mi][ni][j] + bvv);
                }
            }
            __syncthreads();
            unsigned short* dst = Vt + ((size_t)(b * 8 + hbase + ch) * 128) * 4096 + kv0;
#pragma unroll
            for (int it = 0; it < 8; ++it) {
                int u2 = it * 512 + t;
                int row = u2 >> 5, c16 = u2 & 31;
                *reinterpret_cast<short8*>(dst + (size_t)row * 4096 + c16 * 8) =
                    *reinterpret_cast<const short8*>(&CtS[row * 272 + c16 * 8]);
            }
        }
    }
}

// ----------------------------------------------------------- attention ----
// unchanged from round 6 (verified): swapped QK^T, defer-max, packed P,
// dbuf gload_lds, 4 waves, 2 blocks/CU.
__global__ __launch_bounds__(256, 2) void attn_kernel(
    const unsigned short* __restrict__ Qm, const unsigned short* __restrict__ Km,
    const unsigned short* __restrict__ VtG, const float* __restrict__ hidden,
    float* __restrict__ out)
{
    __shared__ __align__(16) unsigned short Kl[2][64 * 128];
    __shared__ __align__(16) unsigned short Vt[2][128 * 64];
    __shared__ __align__(16) unsigned short Pl[64 * 64];

    int t = threadIdx.x, lane = t & 63, w = t >> 6, g = lane >> 4, lr = lane & 15;
    int id = blockIdx.x;
    int swz = (id & 7) * 64 + (id >> 3);
    int qt = swz & 7, h = (swz >> 3) & 7, b = swz >> 6;

    short8 qf[4];
#pragma unroll
    for (int kk = 0; kk < 4; ++kk)
        qf[kk] = *reinterpret_cast<const short8*>(
            Qm + (size_t)(b * 512 + qt * 64 + w * 16 + lr) * 1024 + h * 128 + kk * 32 + g * 8);
    asm volatile("s_waitcnt vmcnt(0)" ::: "memory");

    float m2 = 0.f;
    float l = 0.f;
    f32x4 oacc[8];
#pragma unroll
    for (int nf = 0; nf < 8; ++nf) oacc[nf] = (f32x4)0.f;

    const float SCALE = 0.08838834764831845f;
    const float LOG2E = 1.4426950408889634f;
    const float K1 = SCALE * LOG2E;
    const float THR2 = 11.5f;

    size_t kbase = (size_t)b * 4096 * 1024 + h * 128;
    size_t vbase = ((size_t)(b * 8 + h)) * 128 * 4096;

    auto STAGE_K = [&](int buf, int c) {
        int kv0 = c * 64;
#pragma unroll
        for (int i = 0; i < 4; ++i) {
            int rb = w * 16 + i * 4;
            int row = rb + (lane >> 4);
            int cb = ((lane & 15) * 16) ^ ((row & 7) << 4);
            const char* gp = (const char*)(Km + kbase + (size_t)(kv0 + row) * 1024) + cb;
            GLOAD16(gp, &Kl[buf][rb * 128]);
        }
    };
    auto STAGE_V = [&](int buf, int c) {
        int kv0 = c * 64;
#pragma unroll
        for (int i = 0; i < 4; ++i) {
            int db = w * 32 + i * 8;
            int d = db + (lane >> 3);
            int cb = ((lane & 7) * 16) ^ ((d & 7) << 4);
            const char* gp = (const char*)(VtG + vbase + (size_t)d * 4096 + kv0) + cb;
            GLOAD16(gp, &Vt[buf][db * 64]);
        }
    };

    STAGE_K(0, 0); STAGE_V(0, 0);

    for (int c = 0; c < 64; ++c) {
        int cur = c & 1;
        asm volatile("s_waitcnt vmcnt(0) lgkmcnt(0)" ::: "memory");
        __builtin_amdgcn_sched_barrier(0);
        __builtin_amdgcn_s_barrier();
        if (c < 63) { STAGE_K(cur ^ 1, c + 1); STAGE_V(cur ^ 1, c + 1); }

        f32x4 sacc[4];
#pragma unroll
        for (int nf = 0; nf < 4; ++nf) sacc[nf] = (f32x4)0.f;
#pragma unroll
        for (int kk = 0; kk < 4; ++kk) {
            int cb0 = kk * 64 + g * 16;
            short8 kf[4];
#pragma unroll
            for (int nf = 0; nf < 4; ++nf) {
                int row = nf * 16 + lr;
                kf[nf] = *reinterpret_cast<const short8*>(
                    (const char*)&Kl[cur][0] + row * 256 + (cb0 ^ ((row & 7) << 4)));
            }
            __builtin_amdgcn_s_setprio(1);
#pragma unroll
            for (int nf = 0; nf < 4; ++nf)
                sacc[nf] = __builtin_amdgcn_mfma_f32_16x16x32_bf16(kf[nf], qf[kk], sacc[nf], 0, 0, 0);
            __builtin_amdgcn_s_setprio(0);
        }

        float smax = sacc[0][0];
#pragma unroll
        for (int nf = 0; nf < 4; ++nf)
#pragma unroll
            for (int j = 0; j < 4; ++j) smax = fmaxf(smax, sacc[nf][j]);
        float s2max = smax * K1;
        if (!__all(s2max <= m2 + THR2)) {
            float rm = s2max;
            rm = fmaxf(rm, __shfl_xor(rm, 16));
            rm = fmaxf(rm, __shfl_xor(rm, 32));
            float m2n = fmaxf(m2, rm);
            float corr = exp2f(m2 - m2n);
            l *= corr;
            m2 = m2n;
#pragma unroll
            for (int j = 0; j < 4; ++j) {
                float cj = __shfl(corr, g * 4 + j);
#pragma unroll
                for (int nf = 0; nf < 8; ++nf) oacc[nf][j] *= cj;
            }
        }
        int prow = w * 16 + lr;
        int rsw = (lr & 7) << 4;
#pragma unroll
        for (int nf = 0; nf < 4; ++nf) {
            float p0 = exp2f(sacc[nf][0] * K1 - m2);
            float p1 = exp2f(sacc[nf][1] * K1 - m2);
            float p2 = exp2f(sacc[nf][2] * K1 - m2);
            float p3 = exp2f(sacc[nf][3] * K1 - m2);
            l += (p0 + p1) + (p2 + p3);
            bf16x4 pk;
            pk[0] = (short)f2bf(p0); pk[1] = (short)f2bf(p1);
            pk[2] = (short)f2bf(p2); pk[3] = (short)f2bf(p3);
            *reinterpret_cast<bf16x4*>(
                (char*)Pl + prow * 128 + ((nf * 32 + g * 8) ^ rsw)) = pk;
        }
        asm volatile("s_waitcnt lgkmcnt(0)" ::: "memory");
        __builtin_amdgcn_sched_barrier(0);

#pragma unroll
        for (int kp = 0; kp < 2; ++kp) {
            int cb0 = kp * 64 + g * 16;
            short8 pa = *reinterpret_cast<const short8*>(
                (const char*)Pl + prow * 128 + (cb0 ^ rsw));
#pragma unroll
            for (int nf = 0; nf < 8; ++nf) {
                int d = nf * 16 + lr;
                short8 vb = *reinterpret_cast<const short8*>(
                    (const char*)&Vt[cur][0] + d * 128 + (cb0 ^ ((d & 7) << 4)));
                oacc[nf] = __builtin_amdgcn_mfma_f32_16x16x32_bf16(pa, vb, oacc[nf], 0, 0, 0);
            }
        }
    }

    l += __shfl_xor(l, 16);
    l += __shfl_xor(l, 32);
#pragma unroll
    for (int j = 0; j < 4; ++j) {
        float lj = __shfl(l, g * 4 + j);
        float inv = 1.f / lj;
        int q = qt * 64 + w * 16 + g * 4 + j;
        size_t base = (size_t)(b * 512 + q) * 1024 + h * 128;
#pragma unroll
        for (int nf = 0; nf < 8; ++nf) {
            int d = nf * 16 + lr;
            out[base + d] = hidden[base + d] + oacc[nf][j] * inv;
        }
    }
}

// ---------------------------------------------------------------- host ----
extern "C" void kernel_launch(void* const* d_in, const int* in_sizes, int n_in,
                              void* d_out, int out_size, void* d_ws, size_t ws_size,
                              hipStream_t stream) {
    const float* hidden = (const float*)d_in[0];
    const float* inputs = (const float*)d_in[1];
    const float* ln1w   = (const float*)d_in[2];
    const float* ln1b   = (const float*)d_in[3];
    const float* ln2w   = (const float*)d_in[4];
    const float* ln2b   = (const float*)d_in[5];
    const float* Wq     = (const float*)d_in[6];
    const float* bq     = (const float*)d_in[7];
    const float* Wk     = (const float*)d_in[8];
    const float* bk     = (const float*)d_in[9];
    const float* Wv     = (const float*)d_in[10];
    const float* bv     = (const float*)d_in[11];
    float* out = (float*)d_out;
    char* ws = (char*)d_ws;

    unsigned short* LNh = (unsigned short*)ws;        // 4096x1024 bf16
    unsigned short* LNx = LNh + 4194304;              // 32768x1024
    unsigned short* WqB = LNx + 33554432;             // Wq, then Wk|Wv contiguous
    unsigned short* WkB = WqB + 1048576;
    unsigned short* WvB = WkB + 1048576;
    unsigned short* Qm  = WvB + 1048576;              // 4096x1024
    unsigned short* Km  = Qm + 4194304;               // 32768x1024
    unsigned short* VtG = Km + 33554432;              // [b][h][128 d][4096 kv]

    ln_bf16<<<dim3(9216), dim3(256), 0, stream>>>(hidden, inputs, ln1w, ln1b, ln2w, ln2b, LNh, LNx);
    convert_w<<<dim3(1536), dim3(256), 0, stream>>>(Wq, Wk, Wv, WqB, WkB, WvB);
    gemm_bt<<<dim3(32, 8), dim3(256), 0, stream>>>(LNh, WqB, bq, Qm);
    gemm256<<<dim3(1024), dim3(512), 0, stream>>>(LNx, WkB, bk, bv, Km, VtG, 128, 4);
    attn_kernel<<<dim3(512), dim3(256), 0, stream>>>(Qm, Km, VtG, hidden, out);
}